// Round 1
// 782.193 us; speedup vs baseline: 1.4288x; 1.4288x over previous
//
#include <hip/hip_runtime.h>
#include <math.h>

#define N 8192
#define NF4 2048  // N/4 float4s per row

// Sinkhorn via potentials: u_i = LSE_j(s_ij - v_j); v'_j = LSE_i(s_ij - u_i).
// Fusion: a block owning a row-strip computes u for its rows AND the strip's
// column partial sums from ONE read of s, using
//   exp(s_ij - u_i) = (e_ij / tot_i) * exp(v_j),
//   e_ij = exp(s_ij - v_j - bm_i), tot_i = sum_j e_ij  (all already in regs)
// so v'_j = v_j + log(sum_i e_ij / tot_i). Terms <= 1 -> no online max needed.

__device__ __forceinline__ float wave_max(float m) {
#pragma unroll
  for (int off = 32; off > 0; off >>= 1) m = fmaxf(m, __shfl_xor(m, off, 64));
  return m;
}
__device__ __forceinline__ float wave_sum(float s) {
#pragma unroll
  for (int off = 32; off > 0; off >>= 1) s += __shfl_xor(s, off, 64);
  return s;
}

__device__ __forceinline__ void process_row(
    const float4 (&buf)[8], const float4 (&vv)[8], float (&acc)[32],
    float* red, int parity, int wid, int lane, int t,
    float* __restrict__ u, int row) {
  float a[32];
#pragma unroll
  for (int k = 0; k < 8; ++k) {
    a[4 * k + 0] = buf[k].x - vv[k].x;
    a[4 * k + 1] = buf[k].y - vv[k].y;
    a[4 * k + 2] = buf[k].z - vv[k].z;
    a[4 * k + 3] = buf[k].w - vv[k].w;
  }
  // 4 independent max chains to cut dependent latency
  float m0 = a[0], m1 = a[1], m2 = a[2], m3 = a[3];
#pragma unroll
  for (int k = 1; k < 8; ++k) {
    m0 = fmaxf(m0, a[4 * k + 0]);
    m1 = fmaxf(m1, a[4 * k + 1]);
    m2 = fmaxf(m2, a[4 * k + 2]);
    m3 = fmaxf(m3, a[4 * k + 3]);
  }
  float m = wave_max(fmaxf(fmaxf(m0, m1), fmaxf(m2, m3)));
  float* rp = red + (parity << 3);
  if (lane == 0) rp[wid] = m;
  __syncthreads();
  const float bm = fmaxf(fmaxf(rp[0], rp[1]), fmaxf(rp[2], rp[3]));
  float e[32];
  float s0 = 0.f, s1 = 0.f, s2 = 0.f, s3 = 0.f;
#pragma unroll
  for (int k = 0; k < 8; ++k) {
    e[4 * k + 0] = __expf(a[4 * k + 0] - bm);
    e[4 * k + 1] = __expf(a[4 * k + 1] - bm);
    e[4 * k + 2] = __expf(a[4 * k + 2] - bm);
    e[4 * k + 3] = __expf(a[4 * k + 3] - bm);
    s0 += e[4 * k + 0];
    s1 += e[4 * k + 1];
    s2 += e[4 * k + 2];
    s3 += e[4 * k + 3];
  }
  float ssum = wave_sum((s0 + s1) + (s2 + s3));
  if (lane == 0) rp[4 + wid] = ssum;
  __syncthreads();
  const float tot = rp[4] + rp[5] + rp[6] + rp[7];
  if (t == 0) u[row] = bm + __logf(tot);
  const float inv = 1.0f / tot;
#pragma unroll
  for (int i = 0; i < 32; ++i) acc[i] = fmaf(e[i], inv, acc[i]);
}

// One block per row-strip of R rows. Computes u for its rows (row update with
// current v) and writes the strip's column partial sums pt[strip][j] =
// sum_{i in strip} exp(s_ij - v_j - u_i)   (note: missing exp(v_j) factor is
// added back in combine2 as "+ v_j").
__global__ __launch_bounds__(256) void fused_pass(
    const float* __restrict__ s, const float* __restrict__ v,
    float* __restrict__ u, float* __restrict__ pt, int R, int use_v) {
  const int t = threadIdx.x;
  const int row0 = blockIdx.x * R;
  float4 vv[8];
  if (use_v) {
    const float4* v4 = (const float4*)v;
#pragma unroll
    for (int k = 0; k < 8; ++k) vv[k] = v4[t + k * 256];
  } else {
#pragma unroll
    for (int k = 0; k < 8; ++k) vv[k] = make_float4(0.f, 0.f, 0.f, 0.f);
  }
  float acc[32];
#pragma unroll
  for (int i = 0; i < 32; ++i) acc[i] = 0.f;
  __shared__ float red[16];
  const int wid = t >> 6, lane = t & 63;

  const float4* s4 = (const float4*)s + (size_t)row0 * NF4;
  float4 bufA[8], bufB[8];
#pragma unroll
  for (int k = 0; k < 8; ++k) bufA[k] = s4[t + k * 256];

  for (int r = 0; r < R; r += 2) {
    {  // prefetch row r+1 (R is even)
      const float4* p = s4 + (size_t)(r + 1) * NF4;
#pragma unroll
      for (int k = 0; k < 8; ++k) bufB[k] = p[t + k * 256];
    }
    process_row(bufA, vv, acc, red, 0, wid, lane, t, u, row0 + r);
    if (r + 2 < R) {  // prefetch row r+2
      const float4* p = s4 + (size_t)(r + 2) * NF4;
#pragma unroll
      for (int k = 0; k < 8; ++k) bufA[k] = p[t + k * 256];
    }
    process_row(bufB, vv, acc, red, 1, wid, lane, t, u, row0 + r + 1);
  }

  float4* p4 = (float4*)(pt + (size_t)blockIdx.x * N);
#pragma unroll
  for (int k = 0; k < 8; ++k)
    p4[t + k * 256] =
        make_float4(acc[4 * k], acc[4 * k + 1], acc[4 * k + 2], acc[4 * k + 3]);
}

// Stage 1: group-sum strips. ps[g][j] = sum over per_group strips of pt.
__global__ __launch_bounds__(256) void combine1(const float* __restrict__ pt,
                                                float* __restrict__ ps,
                                                int per_group) {
  const int j = blockIdx.x * 256 + threadIdx.x;
  const int g = blockIdx.y;
  const float* p = pt + (size_t)g * per_group * N + j;
  float acc = 0.f;
  for (int c = 0; c < per_group; ++c) acc += p[(size_t)c * N];
  ps[(size_t)g * N + j] = acc;
}

// Stage 2: v'_j = (add_old ? v_j : 0) + log(sum_g ps[g][j])
__global__ __launch_bounds__(256) void combine2(const float* __restrict__ ps,
                                                float* __restrict__ v,
                                                int ngroups, int add_old) {
  const int j = blockIdx.x * 256 + threadIdx.x;
  float T = 0.f;
  for (int g = 0; g < ngroups; ++g) T += ps[(size_t)g * N + j];
  const float lv = __logf(T);
  v[j] = add_old ? v[j] + lv : lv;
}

// out = exp(s - u_i - v_j)
__global__ __launch_bounds__(256) void finalize_k(const float* __restrict__ s,
                                                  const float* __restrict__ u,
                                                  const float* __restrict__ v,
                                                  float* __restrict__ out) {
  const size_t idx = (size_t)blockIdx.x * 256 + threadIdx.x;  // float4 index
  const int row = (int)(idx >> 11);
  const int c4 = (int)(idx & 2047);
  const float4 sv = ((const float4*)s)[idx];
  const float4 vv = ((const float4*)v)[c4];
  const float ur = u[row];
  float4 o;
  o.x = __expf(sv.x - ur - vv.x);
  o.y = __expf(sv.y - ur - vv.y);
  o.z = __expf(sv.z - ur - vv.z);
  o.w = __expf(sv.w - ur - vv.w);
  ((float4*)out)[idx] = o;
}

extern "C" void kernel_launch(void* const* d_in, const int* in_sizes, int n_in,
                              void* d_out, int out_size, void* d_ws, size_t ws_size,
                              hipStream_t stream) {
  const float* s = (const float*)d_in[0];
  float* out = (float*)d_out;
  float* ws = (float*)d_ws;

  // workspace: u[N] | v[N] | ps[8*N] | pt[nstrips*N]
  const size_t avail = ws_size / sizeof(float);
  int nstrips = 512;  // R=16: 2 blocks/CU at ~190 VGPR, 512-way parallelism
  while (nstrips > 8 && (size_t)(10 + nstrips) * N > avail) nstrips >>= 1;
  const int R = N / nstrips;
  float* u = ws;
  float* v = ws + N;
  float* ps = ws + 2 * N;
  float* pt = ws + 10 * N;
  const int G = (nstrips >= 8) ? 8 : nstrips;
  const int per_group = nstrips / G;

  for (int p = 0; p < 5; ++p) {
    fused_pass<<<nstrips, 256, 0, stream>>>(s, v, u, pt, R, p > 0 ? 1 : 0);
    combine1<<<dim3(N / 256, G), 256, 0, stream>>>(pt, ps, per_group);
    combine2<<<N / 256, 256, 0, stream>>>(ps, v, G, p > 0 ? 1 : 0);
  }
  finalize_k<<<(N / 256) * NF4, 256, 0, stream>>>(s, u, v, out);
}